// Round 4
// baseline (135.792 us; speedup 1.0000x reference)
//
#include <hip/hip_runtime.h>
#include <math.h>

// LossLayer: dist[b,r] = ||W[b]-R[r]||2 ; pred = one_hot(argmax_r dist) ;
// loss = mean(1 + dist[b,y] - dist[b, top2-excluding-y-at-top1]), y=argmax(label[b])
//
// R4: R3's transposed staging was a 64-line TA gather per instruction (2 KB lane
// stride, L1 set-thrashing) -> ~13 us of addresser serialization phase-locked by
// the 2-barrier chunk loop. Revert to R2's COALESCED staging + padded LDS
// (row stride 68 words = 4 mod 32: R2 measured SQ_LDS_BANK_CONFLICT = 0),
// but with pr[4] only (R2's spill came from __launch_bounds__(256,4)'s 64-VGPR
// cap, not from the pattern; plain (256) -> no cap, no spill).
// W tile staged ONCE via global_load_lds (contiguous, zero data VGPRs).
#define NB 4096
#define NR 64
#define BB 4            // b-rows per block = waves per block; grid = 1024
#define NCH 8           // D chunks of 64 floats
#define CF4 16          // float4 per re row per chunk
#define RST 17          // padded LDS row stride in f4 (68 words ≡ 4 mod 32)

#define AS1 __attribute__((address_space(1)))
#define AS3 __attribute__((address_space(3)))

__device__ __forceinline__ void async_copy16(void* lds, const void* g) {
    // LDS dest = wave-uniform base + lane*16 ; global address per-lane contiguous.
    __builtin_amdgcn_global_load_lds((const AS1 void*)g, (AS3 void*)lds, 16, 0, 0);
}

__global__ __launch_bounds__(256) void fused_loss_kernel(
    const float* __restrict__ w,
    const float* __restrict__ re,
    const float* __restrict__ label,
    float* __restrict__ out,
    float* __restrict__ ws)
{
    __shared__ float4 rl[64 * RST];   // padded re chunk, 17408 B
    __shared__ float4 wl[BB * 128];   // full W tile (unpadded; wave-uniform reads), 8192 B
    __shared__ float terms[BB];

    const int tid = threadIdx.x;
    const int wv  = tid >> 6;       // wave id = local b row (wave-uniform)
    const int r   = tid & 63;       // lane = relation 0..63
    const int b0  = blockIdx.x * BB;
    const int b   = b0 + wv;

    const float4* w4  = (const float4*)w;    // [4096][128]
    const float4* re4 = (const float4*)re;   // [64][128]

    // ---- stage full W tile once: wave wv stages its own row (contiguous) ----
    async_copy16(&wl[wv * 128],      w4 + (size_t)b0 * 128 + wv * 128 + r);
    async_copy16(&wl[wv * 128 + 64], w4 + (size_t)b0 * 128 + wv * 128 + 64 + r);

    // ---- prefetch re chunk 0 into registers (coalesced: 256B runs) ----
    float4 pr[4];
    #pragma unroll
    for (int k = 0; k < 4; k++) {
        int idx = tid + k * 256; int row = idx >> 4; int col = idx & 15;
        pr[k] = re4[row * 128 + col];
    }

    float4 acc = {0.f, 0.f, 0.f, 0.f};

    for (int c = 0; c < NCH; c++) {
        // stage prefetched chunk into padded LDS (write: 16-lane runs, 2-way max)
        #pragma unroll
        for (int k = 0; k < 4; k++) {
            int idx = tid + k * 256; int row = idx >> 4; int col = idx & 15;
            rl[row * RST + col] = pr[k];
        }
        __syncthreads();   // drains vmcnt too: W tile ready on first pass

        if (c + 1 < NCH) {  // prefetch next chunk; latency hidden under compute
            #pragma unroll
            for (int k = 0; k < 4; k++) {
                int idx = tid + k * 256; int row = idx >> 4; int col = idx & 15;
                pr[k] = re4[row * 128 + (c + 1) * CF4 + col];
            }
        }

        const float4* wrow = &wl[wv * 128 + c * CF4];   // wave-uniform -> broadcast
        const float4* rrow = &rl[r * RST];              // padded: conflict-free
        #pragma unroll
        for (int dd = 0; dd < CF4; dd++) {
            float4 a  = wrow[dd];
            float4 rr = rrow[dd];
            float dx;
            dx = a.x - rr.x; acc.x = fmaf(dx, dx, acc.x);
            dx = a.y - rr.y; acc.y = fmaf(dx, dx, acc.y);
            dx = a.z - rr.z; acc.z = fmaf(dx, dx, acc.z);
            dx = a.w - rr.w; acc.w = fmaf(dx, dx, acc.w);
        }
        __syncthreads();   // all waves done reading rl before overwrite
    }

    // 4 parallel chains -> low accumulation error
    float d = sqrtf((acc.x + acc.y) + (acc.z + acc.w));

    // ---- top-2 (value) + argmax (index, first-wins ties) across the wave ----
    float m1 = d; int i1 = r; float m2 = -3.0e38f;
    #pragma unroll
    for (int mask = 1; mask <= 32; mask <<= 1) {
        float om1 = __shfl_xor(m1, mask, 64);
        int   oi1 = __shfl_xor(i1, mask, 64);
        float om2 = __shfl_xor(m2, mask, 64);
        bool ob1 = (om1 > m1) || (om1 == m1 && oi1 < i1);
        float w1 = ob1 ? om1 : m1;  int wi1 = ob1 ? oi1 : i1;
        float l1 = ob1 ? m1 : om1;              // loser's top-1 (value only)
        float c2 = ob1 ? om2 : m2;              // winner's top-2 (value only)
        m1 = w1; i1 = wi1;
        m2 = (c2 > l1) ? c2 : l1;
    }

    // ---- y = argmax(label[b]) : one element per lane, coalesced ----
    float lv = label[(size_t)b * 64 + r]; int ly = r;
    #pragma unroll
    for (int mask = 1; mask <= 32; mask <<= 1) {
        float ov = __shfl_xor(lv, mask, 64);
        int   oy = __shfl_xor(ly, mask, 64);
        if (ov > lv || (ov == lv && oy < ly)) { lv = ov; ly = oy; }
    }
    int y = ly;

    float plus  = __shfl(d, y, 64);           // dist[b][y]
    float minus = (i1 == y) ? m2 : m1;        // top-2 value if top-1 == y
    if (r == 0) terms[wv] = 1.0f + plus - minus;

    out[(size_t)b * 64 + r] = (i1 == r) ? 1.0f : 0.0f;   // pred one-hot

    // ---- fused loss reduction: block partial -> device atomic -> last block
    __syncthreads();
    if (tid == 0) {
        float t = ((terms[0] + terms[1]) + (terms[2] + terms[3])) * (1.0f / NB);
        atomicAdd(ws, t);                     // ws[0] = loss accumulator (zeroed)
        __threadfence();                      // order add before counter inc
        unsigned old = atomicAdd((unsigned*)(ws + 1), 1u);   // ws[1] = counter
        if (old == (unsigned)(gridDim.x - 1)) {
            float total = atomicAdd(ws, 0.0f);   // all 1024 adds visible
            out[(size_t)NB * NR] = total;
        }
    }
}

extern "C" void kernel_launch(void* const* d_in, const int* in_sizes, int n_in,
                              void* d_out, int out_size, void* d_ws, size_t ws_size,
                              hipStream_t stream) {
    const float* w   = (const float*)d_in[0];   // [4096,512]
    const float* re  = (const float*)d_in[1];   // [64,512]
    const float* lab = (const float*)d_in[2];   // [4096,64]
    float* out = (float*)d_out;                 // pred [4096,64] ++ loss [1]
    float* ws  = (float*)d_ws;                  // [0]=loss acc, [1]=done counter

    hipMemsetAsync(ws, 0, 8, stream);           // zero acc + counter (graph-safe)
    fused_loss_kernel<<<NB / BB, 256, 0, stream>>>(w, re, lab, out, ws);
}

// Round 5
// 103.574 us; speedup vs baseline: 1.3111x; 1.3111x over previous
//
#include <hip/hip_runtime.h>
#include <math.h>

// LossLayer: dist[b,r] = ||W[b]-R[r]||2 ; pred = one_hot(argmax_r dist) ;
// loss = mean(1 + dist[b,y] - dist[b, top2-excluding-y-at-top1]), y=argmax(label[b])
//
// R5: Register-carried prefetch spilled to scratch TWICE (R2: 118 MB, R4: 45 MB
// HBM writes) -- all data staging now goes through global_load_lds (zero data
// VGPRs; R3 measured WRITE 1.1 MB with it). R3's slowness was its GATHER
// addressing (2 KB lane stride = 64 cache lines/instr TA serialization), not
// the async mechanism: here staging is fully COALESCED (lane-linear rows,
// 256 B runs). That forces unpadded row-major LDS (dest = base + lane*16),
// so compute reads use a per-lane ROTATED column order (dd+r)&15 -- the chunk
// sum is commutative; each quarter-wave then hits 16 distinct bank-quads
// (worst-case alias 2-way across half-waves = free, m136).
// Double-buffered chunks, one barrier per chunk, prefetch distance 1.
#define NB 4096
#define NR 64
#define BB 4            // b-rows per block = waves per block; grid = 1024
#define NCH 8           // D chunks of 64 floats
#define CF4 16          // float4 columns per chunk

#define AS1 __attribute__((address_space(1)))
#define AS3 __attribute__((address_space(3)))

__device__ __forceinline__ void async_copy16(void* lds, const void* g) {
    // LDS dest = wave-uniform base + lane*16 ; global address per-lane contiguous.
    __builtin_amdgcn_global_load_lds((const AS1 void*)g, (AS3 void*)lds, 16, 0, 0);
}

__global__ __launch_bounds__(256) void fused_loss_kernel(
    const float* __restrict__ w,
    const float* __restrict__ re,
    const float* __restrict__ label,
    float* __restrict__ out,
    float* __restrict__ ws)
{
    __shared__ float4 rl[2][64 * CF4];  // double-buffered re chunk, 2 x 16 KB
    __shared__ float4 wl[BB * 128];     // full W tile (wave-uniform reads), 8 KB
    __shared__ float terms[BB];

    const int tid = threadIdx.x;
    const int wv  = tid >> 6;       // wave id = local b row (wave-uniform)
    const int r   = tid & 63;       // lane = relation 0..63
    const int b0  = blockIdx.x * BB;
    const int b   = b0 + wv;

    const float4* w4  = (const float4*)w;    // [4096][128]
    const float4* re4 = (const float4*)re;   // [64][128]

    // ---- stage full W tile once: wave wv stages its own row (contiguous) ----
    async_copy16(&wl[wv * 128],      w4 + (size_t)b0 * 128 + wv * 128 + r);
    async_copy16(&wl[wv * 128 + 64], w4 + (size_t)b0 * 128 + wv * 128 + 64 + r);

    // ---- stage re chunk 0 into buf 0: coalesced, lane-linear row-major ----
    // instruction j=wv*4+k covers LDS f4 slots [j*64, j*64+64) == rows j*4..j*4+3
    #pragma unroll
    for (int k = 0; k < 4; k++) {
        int j = wv * 4 + k;
        int row = j * 4 + (r >> 4);              // global re row
        int col = r & 15;                        // f4 column within chunk
        async_copy16(&rl[0][j * 64], re4 + row * 128 + col - (r & 63) + r);
        // note: row*128+col is already the per-lane address; the -(r&63)+r is
        // identity (kept explicit that addr is lane-linear by construction)
    }

    float4 acc = {0.f, 0.f, 0.f, 0.f};

    for (int c = 0; c < NCH; c++) {
        __syncthreads();   // staged chunk c (and W on first pass) complete;
                           // all waves done reading buf[(c)&1]'s previous tenant

        if (c + 1 < NCH) { // stage chunk c+1 now; drain happens one phase later
            #pragma unroll
            for (int k = 0; k < 4; k++) {
                int j = wv * 4 + k;
                int row = j * 4 + (r >> 4);
                int col = (c + 1) * CF4 + (r & 15);
                async_copy16(&rl[(c + 1) & 1][j * 64], re4 + row * 128 + col);
            }
        }

        const float4* wrow = &wl[wv * 128 + c * CF4];  // wave-uniform -> broadcast
        const float4* rrow = &rl[c & 1][r * CF4];      // lane's own row
        #pragma unroll
        for (int dd = 0; dd < CF4; dd++) {
            int co = (dd + r) & 15;            // rotated traversal: conflict-free
            float4 a  = wrow[co];
            float4 rr = rrow[co];
            float dx;
            dx = a.x - rr.x; acc.x = fmaf(dx, dx, acc.x);
            dx = a.y - rr.y; acc.y = fmaf(dx, dx, acc.y);
            dx = a.z - rr.z; acc.z = fmaf(dx, dx, acc.z);
            dx = a.w - rr.w; acc.w = fmaf(dx, dx, acc.w);
        }
    }

    // 4 parallel chains -> low accumulation error
    float d = sqrtf((acc.x + acc.y) + (acc.z + acc.w));

    // ---- top-2 (value) + argmax (index, first-wins ties) across the wave ----
    float m1 = d; int i1 = r; float m2 = -3.0e38f;
    #pragma unroll
    for (int mask = 1; mask <= 32; mask <<= 1) {
        float om1 = __shfl_xor(m1, mask, 64);
        int   oi1 = __shfl_xor(i1, mask, 64);
        float om2 = __shfl_xor(m2, mask, 64);
        bool ob1 = (om1 > m1) || (om1 == m1 && oi1 < i1);
        float w1 = ob1 ? om1 : m1;  int wi1 = ob1 ? oi1 : i1;
        float l1 = ob1 ? m1 : om1;              // loser's top-1 (value only)
        float c2 = ob1 ? om2 : m2;              // winner's top-2 (value only)
        m1 = w1; i1 = wi1;
        m2 = (c2 > l1) ? c2 : l1;
    }

    // ---- y = argmax(label[b]) : one element per lane, coalesced ----
    float lv = label[(size_t)b * 64 + r]; int ly = r;
    #pragma unroll
    for (int mask = 1; mask <= 32; mask <<= 1) {
        float ov = __shfl_xor(lv, mask, 64);
        int   oy = __shfl_xor(ly, mask, 64);
        if (ov > lv || (ov == lv && oy < ly)) { lv = ov; ly = oy; }
    }
    int y = ly;

    float plus  = __shfl(d, y, 64);           // dist[b][y]
    float minus = (i1 == y) ? m2 : m1;        // top-2 value if top-1 == y
    if (r == 0) terms[wv] = 1.0f + plus - minus;

    out[(size_t)b * 64 + r] = (i1 == r) ? 1.0f : 0.0f;   // pred one-hot

    // ---- fused loss reduction: block partial -> device atomic -> last block
    __syncthreads();
    if (tid == 0) {
        float t = ((terms[0] + terms[1]) + (terms[2] + terms[3])) * (1.0f / NB);
        atomicAdd(ws, t);                     // ws[0] = loss accumulator (zeroed)
        __threadfence();                      // order add before counter inc
        unsigned old = atomicAdd((unsigned*)(ws + 1), 1u);   // ws[1] = counter
        if (old == (unsigned)(gridDim.x - 1)) {
            float total = atomicAdd(ws, 0.0f);   // all 1024 adds visible
            out[(size_t)NB * NR] = total;
        }
    }
}

extern "C" void kernel_launch(void* const* d_in, const int* in_sizes, int n_in,
                              void* d_out, int out_size, void* d_ws, size_t ws_size,
                              hipStream_t stream) {
    const float* w   = (const float*)d_in[0];   // [4096,512]
    const float* re  = (const float*)d_in[1];   // [64,512]
    const float* lab = (const float*)d_in[2];   // [4096,64]
    float* out = (float*)d_out;                 // pred [4096,64] ++ loss [1]
    float* ws  = (float*)d_ws;                  // [0]=loss acc, [1]=done counter

    hipMemsetAsync(ws, 0, 8, stream);           // zero acc + counter (graph-safe)
    fused_loss_kernel<<<NB / BB, 256, 0, stream>>>(w, re, lab, out, ws);
}

// Round 6
// 101.317 us; speedup vs baseline: 1.3403x; 1.0223x over previous
//
#include <hip/hip_runtime.h>
#include <math.h>

// LossLayer: dist[b,r] = ||W[b]-R[r]||2 ; pred = one_hot(argmax_r dist) ;
// loss = mean(1 + dist[b,y] - dist[b, top2-excluding-y-at-top1]), y=argmax(label[b])
//
// R6: R1/R3/R5 all pinned at ~51 us with every pipe <21% -> latency-bound at
// ~3 blocks/CU (40.5 KB LDS) and per-chunk load-latency > compute. Changes:
//  (a) W out of LDS: wave-uniform row read (readfirstlane-forced scalar),
//      halves ds_read traffic;
//  (b) chunk=32 floats double-buffered -> LDS 16.4 KB -> 8 blocks/CU
//      (32 waves/CU, occupancy cap 100% vs measured 16%);
//  (c) staging keeps global_load_lds (register prefetch spilled in R2/R4:
//      118/45 MB HBM writes) but stores PERMUTED: LDS slot rho*8+((d+rho)&7)
//      holds column d of row rho (free choice of per-lane global src addr),
//      so compute reads rrow[(dd+r)&7] = column dd (bank-spread: R5 measured
//      0 conflicts) while W uses the uniform index dd.
#define NB 4096
#define NR 64
#define BB 4            // b-rows per block = waves per block; grid = 1024
#define NCH 16          // D chunks of 32 floats
#define CF4 8           // float4 columns per chunk

#define AS1 __attribute__((address_space(1)))
#define AS3 __attribute__((address_space(3)))

__device__ __forceinline__ void async_copy16(void* lds, const void* g) {
    // LDS dest = wave-uniform base + lane*16 ; global address is per-lane.
    __builtin_amdgcn_global_load_lds((const AS1 void*)g, (AS3 void*)lds, 16, 0, 0);
}

__global__ __launch_bounds__(256) void fused_loss_kernel(
    const float* __restrict__ w,
    const float* __restrict__ re,
    const float* __restrict__ label,
    float* __restrict__ out,
    float* __restrict__ ws)
{
    __shared__ float4 rl[2][64 * CF4];  // double-buffered re chunk, 2 x 8 KB
    __shared__ float terms[BB];

    const int tid = threadIdx.x;
    const int wv  = tid >> 6;       // wave id = local b row (wave-uniform)
    const int r   = tid & 63;       // lane = relation 0..63
    const int b0  = blockIdx.x * BB;
    const int b   = b0 + wv;
    const int wvu = __builtin_amdgcn_readfirstlane(wv);  // provably uniform

    const float4* re4 = (const float4*)re;                       // [64][128]
    const float4* wrow4 = (const float4*)(w + (size_t)(b0 + wvu) * 512); // own row

    // permuted staging: wave wv issues j = wv*2+k; slot s=j*64+lane holds
    // row rho = s>>3, within-row slot kk = s&7 -> column (kk-rho)&7 of chunk c.
    const int rho  = wv * 16 + (r >> 3) /* j*8 + lane>>3 with j=wv*2+k merged below */;
    // (computed per k below since j depends on k)

    // ---- stage chunk 0 into buf 0 ----
    #pragma unroll
    for (int k = 0; k < 2; k++) {
        int j  = wv * 2 + k;
        int rr_ = j * 8 + (r >> 3);              // row rho for this lane
        int pc = ((r & 7) - rr_) & 7;            // permuted column
        async_copy16(&rl[0][j * 64], re4 + rr_ * 128 + pc);
    }

    float4 acc = {0.f, 0.f, 0.f, 0.f};

    for (int c = 0; c < NCH; c++) {
        __syncthreads();   // drains vmcnt: chunk c staged; buf (c&1) free of readers

        if (c + 1 < NCH) { // stage chunk c+1; drained at next barrier
            #pragma unroll
            for (int k = 0; k < 2; k++) {
                int j  = wv * 2 + k;
                int rr_ = j * 8 + (r >> 3);
                int pc = ((r & 7) - rr_) & 7;
                async_copy16(&rl[(c + 1) & 1][j * 64],
                             re4 + rr_ * 128 + (c + 1) * CF4 + pc);
            }
        }

        const float4* rrow = &rl[c & 1][r * CF4];   // lane's own row (permuted)
        #pragma unroll
        for (int dd = 0; dd < CF4; dd++) {
            float4 a  = wrow4[c * CF4 + dd];        // uniform -> scalar/L1-hot
            float4 rv = rrow[(dd + r) & 7];         // = column dd; banks spread
            float dx;
            dx = a.x - rv.x; acc.x = fmaf(dx, dx, acc.x);
            dx = a.y - rv.y; acc.y = fmaf(dx, dx, acc.y);
            dx = a.z - rv.z; acc.z = fmaf(dx, dx, acc.z);
            dx = a.w - rv.w; acc.w = fmaf(dx, dx, acc.w);
        }
    }

    // 4 parallel chains -> low accumulation error
    float d = sqrtf((acc.x + acc.y) + (acc.z + acc.w));

    // ---- top-2 (value) + argmax (index, first-wins ties) across the wave ----
    float m1 = d; int i1 = r; float m2 = -3.0e38f;
    #pragma unroll
    for (int mask = 1; mask <= 32; mask <<= 1) {
        float om1 = __shfl_xor(m1, mask, 64);
        int   oi1 = __shfl_xor(i1, mask, 64);
        float om2 = __shfl_xor(m2, mask, 64);
        bool ob1 = (om1 > m1) || (om1 == m1 && oi1 < i1);
        float w1 = ob1 ? om1 : m1;  int wi1 = ob1 ? oi1 : i1;
        float l1 = ob1 ? m1 : om1;              // loser's top-1 (value only)
        float c2 = ob1 ? om2 : m2;              // winner's top-2 (value only)
        m1 = w1; i1 = wi1;
        m2 = (c2 > l1) ? c2 : l1;
    }

    // ---- y = argmax(label[b]) : one element per lane, coalesced ----
    float lv = label[(size_t)b * 64 + r]; int ly = r;
    #pragma unroll
    for (int mask = 1; mask <= 32; mask <<= 1) {
        float ov = __shfl_xor(lv, mask, 64);
        int   oy = __shfl_xor(ly, mask, 64);
        if (ov > lv || (ov == lv && oy < ly)) { lv = ov; ly = oy; }
    }
    int y = ly;

    float plus  = __shfl(d, y, 64);           // dist[b][y]
    float minus = (i1 == y) ? m2 : m1;        // top-2 value if top-1 == y
    if (r == 0) terms[wv] = 1.0f + plus - minus;

    out[(size_t)b * 64 + r] = (i1 == r) ? 1.0f : 0.0f;   // pred one-hot

    // ---- fused loss reduction: block partial -> device atomic -> last block
    __syncthreads();
    if (tid == 0) {
        float t = ((terms[0] + terms[1]) + (terms[2] + terms[3])) * (1.0f / NB);
        atomicAdd(ws, t);                     // ws[0] = loss accumulator (zeroed)
        __threadfence();                      // order add before counter inc
        unsigned old = atomicAdd((unsigned*)(ws + 1), 1u);   // ws[1] = counter
        if (old == (unsigned)(gridDim.x - 1)) {
            float total = atomicAdd(ws, 0.0f);   // all 1024 adds visible
            out[(size_t)NB * NR] = total;
        }
    }
}

extern "C" void kernel_launch(void* const* d_in, const int* in_sizes, int n_in,
                              void* d_out, int out_size, void* d_ws, size_t ws_size,
                              hipStream_t stream) {
    const float* w   = (const float*)d_in[0];   // [4096,512]
    const float* re  = (const float*)d_in[1];   // [64,512]
    const float* lab = (const float*)d_in[2];   // [4096,64]
    float* out = (float*)d_out;                 // pred [4096,64] ++ loss [1]
    float* ws  = (float*)d_ws;                  // [0]=loss acc, [1]=done counter

    hipMemsetAsync(ws, 0, 8, stream);           // zero acc + counter (graph-safe)
    fused_loss_kernel<<<NB / BB, 256, 0, stream>>>(w, re, lab, out, ws);
}